// Round 2
// baseline (505.665 us; speedup 1.0000x reference)
//
#include <hip/hip_runtime.h>

#define N_ENT   50000
#define CH      128
#define N_EDGES 1600000
#define N_RELM1 10
#define NB      391           // ceil(N_ENT / 128) buckets of 128 heads
#define BCAP    4608          // bucket capacity (verified r8: max bucket fits)
#define PART_BLOCKS 800
#define CHUNK   (N_EDGES / PART_BLOCKS)   // 2000 exactly
#define NRG     (N_ENT / 8)   // 6250 rowgroups of 8 heads
#define NKEY    2048          // (rg:4)(g:4)(r:3) sort bins per bucket
#define EPS_N   1e-12f

typedef int v16i __attribute__((ext_vector_type(16)));
typedef int v8i  __attribute__((ext_vector_type(8)));

__device__ __forceinline__ unsigned int f2bf_bits(float f) {
    unsigned int x = __float_as_uint(f);
    return (x + 0x7FFFu + ((x >> 16) & 1u)) >> 16;   // RNE; values are finite
}

// 16-dword scalar load of csr metadata (uniform address). No wait here.
__device__ __forceinline__ v16i sload16(const int* p, int boff) {
    v16i r;
    asm volatile("s_load_dwordx16 %0, %1, %2"
                 : "=s"(r) : "s"(p), "s"(boff));
    return r;
}
__device__ __forceinline__ v8i sload8(const int* p) {
    v8i r;
    asm volatile("s_load_dwordx8 %0, %1, 0" : "=s"(r) : "s"(p));
    return r;
}
// Full lgkm wait with the tuples as operands so consumers are dataflow-ordered.
__device__ __forceinline__ void swait16(v16i& r) {
    asm volatile("s_waitcnt lgkmcnt(0)" : "+s"(r));
}
__device__ __forceinline__ void swait16_8(v16i& a, v8i& d) {
    asm volatile("s_waitcnt lgkmcnt(0)" : "+s"(a), "+s"(d));
}

// Per block: ONE pass over its 2000 edges, stage entry+bucket in LDS,
// histogram, scan, LDS bin-scatter, coalesced write-out. Fused bf16 cvt.
// entry = tail(16) | rel(4)<<16 | hlow(7)<<20
__global__ __launch_bounds__(256) void gc_part_kernel(const int* __restrict__ head,
                                                      const int* __restrict__ tail,
                                                      const int* __restrict__ etyp,
                                                      int* __restrict__ barr,
                                                      int* __restrict__ pack,
                                                      const float* __restrict__ ent,
                                                      unsigned int* __restrict__ emb) {
    __shared__ int hist[512];                // NB bins padded
    __shared__ int boff_s[512];
    __shared__ int fctr[512];
    __shared__ int psum[256];
    __shared__ int stageE[CHUNK];            // raw entries (8 KB)
    __shared__ unsigned short stageB[CHUNK]; // bucket ids (4 KB)
    __shared__ int stage2[CHUNK];            // binned entries (8 KB)
    int tid = threadIdx.x, blk = blockIdx.x;
    for (int i = tid; i < 512; i += 256) { hist[i] = 0; fctr[i] = 0; }
    __syncthreads();
    int lo = blk * CHUNK;
    for (int i = tid; i < CHUNK; i += 256) {
        int e = lo + i;
        int h = head[e];
        int b = h >> 7;
        stageE[i] = (tail[e] & 0xFFFF) | ((etyp[e] - 1) << 16) | ((h & 127) << 20);
        stageB[i] = (unsigned short)b;
        atomicAdd(&hist[b], 1);
    }
    __syncthreads();
    // exclusive scan of 512 bins: 2 bins/thread + 256-ladder
    int a0 = hist[2 * tid], a1 = hist[2 * tid + 1];
    int s2 = a0 + a1;
    psum[tid] = s2;
    __syncthreads();
    for (int d = 1; d < 256; d <<= 1) {
        int t = (tid >= d) ? psum[tid - d] : 0;
        __syncthreads();
        psum[tid] += t;
        __syncthreads();
    }
    int excl = psum[tid] - s2;
    boff_s[2 * tid] = excl;
    boff_s[2 * tid + 1] = excl + a0;
    __syncthreads();
    for (int i = tid; i < CHUNK; i += 256) {
        int b = stageB[i];
        int pos = boff_s[b] + atomicAdd(&fctr[b], 1);
        stage2[pos] = stageE[i];
    }
    __syncthreads();
    for (int i = tid; i < CHUNK; i += 256) barr[lo + i] = stage2[i];
    for (int i = tid; i < NB; i += 256)
        pack[blk * NB + i] = (boff_s[i] << 8) | fctr[i];
    // fused cvt (independent streaming work)
    for (int i = blk * 256 + tid; i < N_ENT * (CH / 2); i += PART_BLOCKS * 256) {
        float2 v = *(const float2*)(ent + 2 * (size_t)i);
        emb[i] = f2bf_bits(v.x) | (f2bf_bits(v.y) << 16);
    }
}

// per bucket: gather the 800 part-block windows to LDS, then sort entries by
// key = (rowgroup:4 | tailgroup:4 | row:3). Emits per-row degree, per-rowgroup
// csr start, and csr entries (tail|rel|r) ordered by tail-group so the hop
// kernel's chip-wide gather window is ~1-2 MB at any instant (L2-resident).
__global__ __launch_bounds__(1024) void gc_place_kernel(const int* __restrict__ barr,
                                                        const int* __restrict__ pack,
                                                        int* __restrict__ deg_arr,
                                                        int* __restrict__ rg_off,
                                                        int* __restrict__ csr) {
    __shared__ int ent_s[BCAP];
    __shared__ int psum[1024];
    __shared__ int kcnt[NKEY];
    __shared__ int kctr[NKEY];
    __shared__ int kbase[NKEY];
    int b = blockIdx.x, tid = threadIdx.x;
    kcnt[tid] = 0; kcnt[tid + 1024] = 0;
    kctr[tid] = 0; kctr[tid + 1024] = 0;
    int c = 0, o = 0;
    if (tid < PART_BLOCKS) {
        int pk = pack[tid * NB + b];
        c = pk & 255;
        o = pk >> 8;
    }
    psum[tid] = c;
    __syncthreads();
    for (int d = 1; d < 1024; d <<= 1) {
        int t = (tid >= d) ? psum[tid - d] : 0;
        __syncthreads();
        psum[tid] += t;
        __syncthreads();
    }
    int my_off = psum[tid] - c;
    int n = psum[1023];
    const int* src = barr + tid * CHUNK + o;
    for (int k = 0; k < c; ++k) ent_s[my_off + k] = src[k];
    __syncthreads();
    // histogram over 2048 keys
    for (int i = tid; i < n; i += 1024) {
        int e = ent_s[i];
        int hl = (e >> 20) & 127;
        int key = ((hl >> 3) << 7) | (((e & 0xFFFF) >> 12) << 3) | (hl & 7);
        atomicAdd(&kcnt[key], 1);
    }
    __syncthreads();
    // per-row degree (reads raw kcnt; kcnt is not modified below)
    if (tid < 128) {
        int rgl = tid >> 3, r = tid & 7;
        int d = 0;
        #pragma unroll
        for (int g = 0; g < 16; ++g) d += kcnt[(rgl << 7) | (g << 3) | r];
        int h = (b << 7) + tid;
        if (h < N_ENT) deg_arr[h] = d;
    }
    // exclusive scan of 2048 bins: 2 bins/thread + 1024-ladder
    int a0 = kcnt[2 * tid], a1 = kcnt[2 * tid + 1];
    int s2 = a0 + a1;
    psum[tid] = s2;
    __syncthreads();
    for (int d = 1; d < 1024; d <<= 1) {
        int t = (tid >= d) ? psum[tid - d] : 0;
        __syncthreads();
        psum[tid] += t;
        __syncthreads();
    }
    int excl = psum[tid] - s2;
    kbase[2 * tid] = excl;
    kbase[2 * tid + 1] = excl + a0;
    __syncthreads();
    int lo = b * BCAP;
    if (tid < 16) {
        int grg = (b << 4) + tid;
        if (grg < NRG) rg_off[grg] = lo + kbase[tid << 7];
    }
    for (int i = tid; i < n; i += 1024) {
        int e = ent_s[i];
        int hl = (e >> 20) & 127;
        int key = ((hl >> 3) << 7) | (((e & 0xFFFF) >> 12) << 3) | (hl & 7);
        int pos = lo + kbase[key] + atomicAdd(&kctr[key], 1);
        csr[pos] = (e & 0xFFFFF) | ((hl & 7) << 20);   // tail | rel<<16 | r<<20
    }
}

// one wave64 per 8 rows (rowgroup). All 6250 waves (1563 blocks) are
// co-resident from t=0; each sweeps its tail-group-sorted edge list
// monotonically, so the chip-wide gather window stays L2-sized.
// 8 accumulator pairs live in named VGPRs; per-edge row id is a uniform
// scalar (csr bits 20-22) -> scc branch, no divergence.
// mode 0: write bf16 dst. mode 1: fuse res = ent + bf16(y1) + bf16(y2) + y3.
__global__ __launch_bounds__(256, 8) void gc_hop_kernel(
        const unsigned int* __restrict__ src,     // bf16x2 per uint
        const int* __restrict__ deg_arr,
        const int* __restrict__ rg_off,
        const int* __restrict__ csr,
        const float* __restrict__ wt,
        unsigned int* __restrict__ dst,
        float* __restrict__ res,
        const float* __restrict__ ent,
        const unsigned int* __restrict__ yprev,
        int mode) {
    __shared__ float wt_s[N_RELM1 * CH];
    for (int i = threadIdx.x; i < N_RELM1 * CH; i += 256) wt_s[i] = wt[i];
    __syncthreads();

    int wave = threadIdx.x >> 6, lane = threadIdx.x & 63;
    int rg = __builtin_amdgcn_readfirstlane(blockIdx.x * 4 + wave);
    if (rg >= NRG) return;    // no barriers below

    v8i D = sload8(deg_arr + (size_t)rg * 8);
    int seg = __builtin_amdgcn_readfirstlane(rg_off[rg]);
    v16i A = sload16(csr, seg << 2);
    swait16_8(A, D);

    int nedges = D[0] + D[1] + D[2] + D[3] + D[4] + D[5] + D[6] + D[7];

    float ax0 = 0.f, ay0 = 0.f, ax1 = 0.f, ay1 = 0.f;
    float ax2 = 0.f, ay2 = 0.f, ax3 = 0.f, ay3 = 0.f;
    float ax4 = 0.f, ay4 = 0.f, ax5 = 0.f, ay5 = 0.f;
    float ax6 = 0.f, ay6 = 0.f, ax7 = 0.f, ay7 = 0.f;

#define EDGE(pk) { \
        int pk_ = (pk); \
        unsigned v = src[(unsigned)(pk_ & 0xFFFF) * 64u + (unsigned)lane]; \
        float2 w = *(const float2*)(&wt_s[((pk_ >> 16) & 15) * CH + 2 * lane]); \
        float vx = __uint_as_float(v << 16); \
        float vy = __uint_as_float(v & 0xFFFF0000u); \
        switch (pk_ >> 20) { \
        case 0: ax0 = fmaf(vx, w.x, ax0); ay0 = fmaf(vy, w.y, ay0); break; \
        case 1: ax1 = fmaf(vx, w.x, ax1); ay1 = fmaf(vy, w.y, ay1); break; \
        case 2: ax2 = fmaf(vx, w.x, ax2); ay2 = fmaf(vy, w.y, ay2); break; \
        case 3: ax3 = fmaf(vx, w.x, ax3); ay3 = fmaf(vy, w.y, ay3); break; \
        case 4: ax4 = fmaf(vx, w.x, ax4); ay4 = fmaf(vy, w.y, ay4); break; \
        case 5: ax5 = fmaf(vx, w.x, ax5); ay5 = fmaf(vy, w.y, ay5); break; \
        case 6: ax6 = fmaf(vx, w.x, ax6); ay6 = fmaf(vy, w.y, ay6); break; \
        default: ax7 = fmaf(vx, w.x, ax7); ay7 = fmaf(vy, w.y, ay7); break; \
        } }

    if (nedges > 0) {
        int nch = (nedges + 15) >> 4;
        int boff = (seg + 16) << 2;
        for (int c = 0; c < nch - 1; ++c, boff += 64) {
            v16i B = sload16(csr, boff);       // prefetch next 16 entries
            #pragma unroll
            for (int u = 0; u < 16; ++u) EDGE(A[u]);
            swait16(B);                        // covered by the 16 gathers+FMAs
            A = B;
        }
        int rem = nedges - ((nch - 1) << 4);   // 1..16
        #pragma unroll
        for (int u = 0; u < 16; ++u)
            if (u < rem) EDGE(A[u]);           // uniform scc branches
    }
#undef EDGE

#define ROWOUT(r, axr, ayr) { \
        int row = (rg << 3) + r; \
        float invd = 1.0f / fmaxf((float)D[r], 1.0f); \
        float x0 = axr * invd, x1 = ayr * invd; \
        float s = x0 * x0 + x1 * x1; \
        _Pragma("unroll") \
        for (int o = 32; o; o >>= 1) s += __shfl_xor(s, o, 64); \
        float inv = 1.0f / fmaxf(sqrtf(s), EPS_N); \
        float y0 = x0 * inv, y1v = x1 * inv; \
        if (mode == 0) { \
            dst[(row << 6) + lane] = f2bf_bits(y0) | (f2bf_bits(y1v) << 16); \
        } else { \
            unsigned p1 = yprev[(row << 6) + lane]; \
            unsigned p2 = src[(row << 6) + lane]; \
            int base = (row << 7) + 2 * lane; \
            float2 e = *(const float2*)(ent + base); \
            float2 o2; \
            o2.x = e.x + __uint_as_float(p1 << 16) \
                       + __uint_as_float(p2 << 16) + y0; \
            o2.y = e.y + __uint_as_float(p1 & 0xFFFF0000u) \
                       + __uint_as_float(p2 & 0xFFFF0000u) + y1v; \
            *(float2*)(res + base) = o2; \
        } }

    ROWOUT(0, ax0, ay0);
    ROWOUT(1, ax1, ay1);
    ROWOUT(2, ax2, ay2);
    ROWOUT(3, ax3, ay3);
    ROWOUT(4, ax4, ay4);
    ROWOUT(5, ax5, ay5);
    ROWOUT(6, ax6, ay6);
    ROWOUT(7, ax7, ay7);
#undef ROWOUT
}

extern "C" void kernel_launch(void* const* d_in, const int* in_sizes, int n_in,
                              void* d_out, int out_size, void* d_ws, size_t ws_size,
                              hipStream_t stream) {
    const float* ent  = (const float*)d_in[0];
    const int*   eidx = (const int*)d_in[1];   // [2, E]: head row 0, tail row 1
    const int*   etyp = (const int*)d_in[2];
    const float* wt   = (const float*)d_in[3];
    float*       res  = (float*)d_out;

    const int* head = eidx;
    const int* tail = eidx + N_EDGES;

    // workspace layout (~41 MB). csr is deliberately NOT last: the x16 scalar
    // metadata load may read up to 60 B past a segment; overflow lands in barr.
    unsigned int* embA = (unsigned int*)d_ws;                 // 12.8 MB
    unsigned int* embB = embA + (size_t)N_ENT * 64;           // 12.8 MB
    int* deg_arr = (int*)(embB + (size_t)N_ENT * 64);         // N_ENT
    int* rg_off  = deg_arr + N_ENT;                           // NRG (pad 6272)
    int* csr  = rg_off + 6272;                                // NB*BCAP 7.2 MB
    int* barr = csr + (size_t)NB * BCAP;                      // N_EDGES 6.4 MB
    int* pack = barr + N_EDGES;                               // 1.25 MB

    gc_part_kernel<<<PART_BLOCKS, 256, 0, stream>>>(head, tail, etyp, barr, pack,
                                                    ent, embA);
    gc_place_kernel<<<NB, 1024, 0, stream>>>(barr, pack, deg_arr, rg_off, csr);

    const int hop_grid = (NRG + 3) / 4;   // 1563 blocks, all co-resident
    // hop1: y1 -> embB
    gc_hop_kernel<<<hop_grid, 256, 0, stream>>>(embA, deg_arr, rg_off, csr, wt,
                                                embB, res, ent, embB, 0);
    // hop2: y2 -> embA
    gc_hop_kernel<<<hop_grid, 256, 0, stream>>>(embB, deg_arr, rg_off, csr, wt,
                                                embA, res, ent, embB, 0);
    // hop3: gathers from embA (y2), reads embB (y1) + ent, writes res only
    gc_hop_kernel<<<hop_grid, 256, 0, stream>>>(embA, deg_arr, rg_off, csr, wt,
                                                embB, res, ent, embB, 1);
}